// Round 2
// baseline (7650.188 us; speedup 1.0000x reference)
//
#include <hip/hip_runtime.h>
#include <hip/hip_cooperative_groups.h>
#include <math.h>

namespace cg = cooperative_groups;

typedef short bf16x8 __attribute__((ext_vector_type(8)));
typedef float f32x4 __attribute__((ext_vector_type(4)));
typedef unsigned long long ull;
typedef unsigned int uint;
typedef unsigned short ushort;

#define Bz 32
#define Tz 50
#define Sz 40
#define Vz 32000
#define Dz 512
#define Hz 1024
#define Mz 1600   // B*T rows
#define Mp 1664   // padded to 13*128

// ws float-offsets
#define NF_GX   (Mz * 4096)        // gates_x [row=b*50+t][4096] (biases folded)
#define NF_GH   (4096 * 32)        // gate_h [j][b]
#define NF_V32  (1024 * 32)

__device__ __forceinline__ ushort f2bf(float f) {
    uint u = __builtin_bit_cast(uint, f);
    return (ushort)((u + 0x7FFFu + ((u >> 16) & 1u)) >> 16);
}
__device__ __forceinline__ float bf2f(ushort h) {
    uint u = ((uint)h) << 16;
    return __builtin_bit_cast(float, u);
}
__device__ __forceinline__ float sigf(float x) { return 1.f / (1.f + expf(-x)); }

// ---------------- k_pre: init hxT, cx, zero HXA pad rows ----------------
__global__ __launch_bounds__(256) void k_pre(float* hxT, float* cx, ushort* hxa_hi, ushort* hxa_lo,
                                             const float* h0, const float* c0) {
    int gid = blockIdx.x * 256 + threadIdx.x;
    if (gid < 32768) {
        int h = gid >> 5, b = gid & 31;
        hxT[gid] = h0[b * Hz + h];
    } else if (gid < 65536) {
        int g = gid - 32768;
        cx[g] = c0[g];
    } else {
        int g = gid - 65536;           // [0, 65536): pad rows 1600..1663
        hxa_hi[(long)Mz * Hz + g] = 0;
        hxa_lo[(long)Mz * Hz + g] = 0;
    }
}

// ---------------- k_xgemm: gates_x = emb[tok] @ Wih^T + bih + bhh ----------------
__global__ __launch_bounds__(256) void k_xgemm(const float* __restrict__ emb, const int* __restrict__ tok,
                                               const float* __restrict__ Wih, const float* __restrict__ bih,
                                               const float* __restrict__ bhh, float* __restrict__ gx) {
    int mt = blockIdx.x >> 5, nt = blockIdx.x & 31;
    __shared__ float As[16][132];
    __shared__ float Bs[16][132];
    int tid = threadIdx.x;
    int ty = tid >> 4, tx = tid & 15;
    float acc[8][8];
#pragma unroll
    for (int i = 0; i < 8; i++)
#pragma unroll
        for (int j = 0; j < 8; j++) acc[i][j] = 0.f;

    for (int kb = 0; kb < Dz; kb += 16) {
        int f0 = tid * 2;
#pragma unroll
        for (int q = 0; q < 2; q++) {
            int f = f0 + q;
            int m = f >> 2, kq = (f & 3) * 4;
            int r = mt * 128 + m;
            float4 v = {0.f, 0.f, 0.f, 0.f};
            if (r < Mz) v = *(const float4*)(emb + (long)tok[r] * Dz + kb + kq);
            As[kq + 0][m] = v.x; As[kq + 1][m] = v.y; As[kq + 2][m] = v.z; As[kq + 3][m] = v.w;
            float4 w = *(const float4*)(Wih + (long)(nt * 128 + m) * Dz + kb + kq);
            Bs[kq + 0][m] = w.x; Bs[kq + 1][m] = w.y; Bs[kq + 2][m] = w.z; Bs[kq + 3][m] = w.w;
        }
        __syncthreads();
#pragma unroll
        for (int kk = 0; kk < 16; kk++) {
            float a[8], bb2[8];
            *(float4*)(a)       = *(float4*)&As[kk][ty * 8];
            *(float4*)(a + 4)   = *(float4*)&As[kk][ty * 8 + 4];
            *(float4*)(bb2)     = *(float4*)&Bs[kk][tx * 8];
            *(float4*)(bb2 + 4) = *(float4*)&Bs[kk][tx * 8 + 4];
#pragma unroll
            for (int i = 0; i < 8; i++)
#pragma unroll
                for (int j = 0; j < 8; j++) acc[i][j] += a[i] * bb2[j];
        }
        __syncthreads();
    }
    int vcol = nt * 128 + tx * 8;
    float bias[8];
#pragma unroll
    for (int j = 0; j < 8; j++) bias[j] = bih[vcol + j] + bhh[vcol + j];
#pragma unroll
    for (int i = 0; i < 8; i++) {
        int r = mt * 128 + ty * 8 + i;
        if (r >= Mz) break;
        float4 o0 = {acc[i][0] + bias[0], acc[i][1] + bias[1], acc[i][2] + bias[2], acc[i][3] + bias[3]};
        float4 o1 = {acc[i][4] + bias[4], acc[i][5] + bias[5], acc[i][6] + bias[6], acc[i][7] + bias[7]};
        *(float4*)(gx + (long)r * 4096 + vcol)     = o0;
        *(float4*)(gx + (long)r * 4096 + vcol + 4) = o1;
    }
}

// ---------------- k_rec: cooperative, all 50 steps ----------------
__global__ __launch_bounds__(512, 1) void k_rec(
    float* __restrict__ gates_x, float* __restrict__ gate_h, float* __restrict__ hxT,
    float* __restrict__ ctxT, float* __restrict__ cx,
    ushort* __restrict__ hxa_hi, ushort* __restrict__ hxa_lo,
    const float* __restrict__ Whh, const float* __restrict__ Wht,
    const float* __restrict__ enc, const float* __restrict__ bht) {
    cg::grid_group grid = cg::this_grid();
    int wid = blockIdx.x, tid = threadIdx.x;
    int b = tid & 31;
    __shared__ float hxs[Hz];
    __shared__ float sc[64];
    __shared__ float aw[Sz];
    __shared__ float red[4][4][32];

    for (int t = 0; t <= Tz; ++t) {
        if (t < Tz) {
            // gate_h[j][b] = Whh[j,:] . hx[:,b]   (j = wid*16 + slot)
            int j = wid * 16 + (tid >> 5);
            const float* wr = Whh + (long)j * Hz;
            float a0 = 0.f, a1 = 0.f, a2 = 0.f, a3 = 0.f;
#pragma unroll 2
            for (int kk = 0; kk < Hz; kk += 8) {
                float4 w0 = *(const float4*)(wr + kk);
                float4 w1 = *(const float4*)(wr + kk + 4);
                const float* xp = hxT + kk * 32 + b;
                a0 += w0.x * xp[0]   + w0.y * xp[32];
                a1 += w0.z * xp[64]  + w0.w * xp[96];
                a2 += w1.x * xp[128] + w1.y * xp[160];
                a3 += w1.z * xp[192] + w1.w * xp[224];
            }
            gate_h[j * 32 + b] = (a0 + a1) + (a2 + a3);
        }
        if (t > 0) {
            // ht-GEMM for step t-1: HXA[row(b,t-1)][j] = tanh(Wht[j,:] . cat(ctx,hx)[:,b] + bht[j])
            int jsl = (tid >> 5) & 3, kq = tid >> 7;
            int j = wid * 4 + jsl;
            const float* wr = Wht + (long)j * 2048 + kq * 512;
            const float* src = (kq < 2) ? (ctxT + kq * 512 * 32) : (hxT + (kq - 2) * 512 * 32);
            float a0 = 0.f, a1 = 0.f, a2 = 0.f, a3 = 0.f;
#pragma unroll 2
            for (int kk = 0; kk < 512; kk += 8) {
                float4 w0 = *(const float4*)(wr + kk);
                float4 w1 = *(const float4*)(wr + kk + 4);
                const float* xp = src + kk * 32 + b;
                a0 += w0.x * xp[0]   + w0.y * xp[32];
                a1 += w0.z * xp[64]  + w0.w * xp[96];
                a2 += w1.x * xp[128] + w1.y * xp[160];
                a3 += w1.z * xp[192] + w1.w * xp[224];
            }
            red[jsl][kq][b] = (a0 + a1) + (a2 + a3);
            __syncthreads();
            if (kq == 0) {
                float s = red[jsl][0][b] + red[jsl][1][b] + red[jsl][2][b] + red[jsl][3][b];
                float v = tanhf(s + bht[j]);
                long row = (long)b * Tz + (t - 1);
                ushort hi = f2bf(v);
                hxa_hi[row * Hz + j] = hi;
                hxa_lo[row * Hz + j] = f2bf(v - bf2f(hi));
            }
        }
        grid.sync();
        if (t < Tz) {
            if (wid < 32) {
                int bb = wid;
                const float* gx = gates_x + ((long)bb * Tz + t) * 4096;
                float gs[8];
#pragma unroll
                for (int m = 0; m < 8; ++m) {
                    int j = tid + 512 * m;
                    gs[m] = gx[j] + gate_h[j * 32 + bb];
                }
                float* cxb = cx + (long)bb * Hz;
#pragma unroll
                for (int r = 0; r < 2; ++r) {
                    int h = tid + 512 * r;
                    float ig = sigf(gs[r]), fg = sigf(gs[2 + r]);
                    float gg = tanhf(gs[4 + r]), og = sigf(gs[6 + r]);
                    float c = fg * cxb[h] + ig * gg;
                    float hv = og * tanhf(c);
                    cxb[h] = c;
                    hxT[h * 32 + bb] = hv;
                    hxs[h] = hv;
                }
                __syncthreads();
                int wave = tid >> 6, lane = tid & 63;
                float hreg[16];
#pragma unroll
                for (int u = 0; u < 16; ++u) hreg[u] = hxs[lane * 16 + u];
                const float* eb = enc + (long)bb * Sz * Hz;
                for (int s = wave; s < Sz; s += 8) {
                    const float* er = eb + (long)s * Hz + lane * 16;
                    float sum = 0.f;
#pragma unroll
                    for (int q = 0; q < 4; ++q) {
                        float4 e4 = *(const float4*)(er + q * 4);
                        sum += e4.x * hreg[q*4] + e4.y * hreg[q*4+1] + e4.z * hreg[q*4+2] + e4.w * hreg[q*4+3];
                    }
#pragma unroll
                    for (int off = 32; off >= 1; off >>= 1) sum += __shfl_xor(sum, off);
                    if (lane == 0) sc[s] = sum;
                }
                __syncthreads();
                if (tid < 64) {
                    float v = (tid < Sz) ? sc[tid] : -3.402823e38f;
                    float mx = v;
#pragma unroll
                    for (int off = 32; off >= 1; off >>= 1) mx = fmaxf(mx, __shfl_xor(mx, off));
                    float e = (tid < Sz) ? expf(v - mx) : 0.f;
                    float ssum = e;
#pragma unroll
                    for (int off = 32; off >= 1; off >>= 1) ssum += __shfl_xor(ssum, off);
                    if (tid < Sz) aw[tid] = e / ssum;
                }
                __syncthreads();
#pragma unroll
                for (int r = 0; r < 2; ++r) {
                    int h = tid + 512 * r;
                    float a = 0.f;
                    for (int s = 0; s < Sz; ++s) a += aw[s] * eb[(long)s * Hz + h];
                    ctxT[h * 32 + bb] = a;
                }
            }
            grid.sync();
        }
    }
}

// ---------------- k_voc2: split-bf16 MFMA GEMM + fused row-argmax keys ----------------
__global__ __launch_bounds__(256, 1) void k_voc2(
    const ushort* __restrict__ Ah, const ushort* __restrict__ Al,
    const float* __restrict__ W, const float* __restrict__ bvoc,
    float* __restrict__ out, ull* __restrict__ keys) {
    __shared__ ushort sAh[128][40];
    __shared__ ushort sAl[128][40];
    __shared__ ushort sBh[128][40];
    __shared__ ushort sBl[128][40];
    int bid = blockIdx.x;
    int mt = bid / 250, nt = bid % 250;
    int tid = threadIdx.x;
    int row = tid >> 1, half = tid & 1;
    int wv = tid >> 6, lane = tid & 63;
    int wr = wv >> 1, wc = wv & 1;
    int m0 = wr * 64, n0 = wc * 64;
    int r16 = lane & 15, kg = lane >> 4, k0 = kg * 8;

    f32x4 acc[4][4];
#pragma unroll
    for (int i = 0; i < 4; i++)
#pragma unroll
        for (int j = 0; j < 4; j++) acc[i][j] = (f32x4){0.f, 0.f, 0.f, 0.f};

    long arow = (long)(mt * 128 + row) * Hz;           // padded rows are zeroed
    long wrow = (long)(nt * 128 + row) * Hz;

    for (int kb = 0; kb < Hz; kb += 32) {
        {
            const ushort* pa = Ah + arow + kb + half * 16;
            uint4 a0 = *(const uint4*)pa;
            uint4 a1 = *(const uint4*)(pa + 8);
            *(uint4*)&sAh[row][half * 16]     = a0;
            *(uint4*)&sAh[row][half * 16 + 8] = a1;
            const ushort* pl = Al + arow + kb + half * 16;
            uint4 l0 = *(const uint4*)pl;
            uint4 l1 = *(const uint4*)(pl + 8);
            *(uint4*)&sAl[row][half * 16]     = l0;
            *(uint4*)&sAl[row][half * 16 + 8] = l1;
            const float* pw = W + wrow + kb + half * 16;
            ushort hh[16], ll[16];
#pragma unroll
            for (int q = 0; q < 16; q += 4) {
                float4 w4 = *(const float4*)(pw + q);
                float vv[4] = {w4.x, w4.y, w4.z, w4.w};
#pragma unroll
                for (int e = 0; e < 4; ++e) {
                    ushort h_ = f2bf(vv[e]);
                    hh[q + e] = h_;
                    ll[q + e] = f2bf(vv[e] - bf2f(h_));
                }
            }
            *(uint4*)&sBh[row][half * 16]     = *(uint4*)&hh[0];
            *(uint4*)&sBh[row][half * 16 + 8] = *(uint4*)&hh[8];
            *(uint4*)&sBl[row][half * 16]     = *(uint4*)&ll[0];
            *(uint4*)&sBl[row][half * 16 + 8] = *(uint4*)&ll[8];
        }
        __syncthreads();
        bf16x8 af[4], alf[4], bhf[4], blf[4];
#pragma unroll
        for (int i = 0; i < 4; ++i) {
            af[i]  = *(const bf16x8*)&sAh[m0 + i * 16 + r16][k0];
            alf[i] = *(const bf16x8*)&sAl[m0 + i * 16 + r16][k0];
            bhf[i] = *(const bf16x8*)&sBh[n0 + i * 16 + r16][k0];
            blf[i] = *(const bf16x8*)&sBl[n0 + i * 16 + r16][k0];
        }
#pragma unroll
        for (int i = 0; i < 4; ++i)
#pragma unroll
            for (int jn = 0; jn < 4; ++jn) {
                acc[i][jn] = __builtin_amdgcn_mfma_f32_16x16x32_bf16(af[i],  bhf[jn], acc[i][jn], 0, 0, 0);
                acc[i][jn] = __builtin_amdgcn_mfma_f32_16x16x32_bf16(af[i],  blf[jn], acc[i][jn], 0, 0, 0);
                acc[i][jn] = __builtin_amdgcn_mfma_f32_16x16x32_bf16(alf[i], bhf[jn], acc[i][jn], 0, 0, 0);
            }
        __syncthreads();
    }
    // epilogue: write C + bias, fused per-row argmax over this WG's 128 cols
#pragma unroll
    for (int i = 0; i < 4; ++i) {
        int gr0 = mt * 128 + m0 + i * 16 + kg * 4;
#pragma unroll
        for (int reg = 0; reg < 4; ++reg) {
            int gr = gr0 + reg;
            bool valid = gr < Mz;
            float bestv = -3.402823e38f;
            int bestc = 0;
#pragma unroll
            for (int jn = 0; jn < 4; ++jn) {
                int gc = nt * 128 + n0 + jn * 16 + r16;
                float v = acc[i][jn][reg] + bvoc[gc];
                if (valid) out[(long)gr * Vz + gc] = v;
                if (v > bestv) { bestv = v; bestc = gc; }
            }
#pragma unroll
            for (int off = 1; off < 16; off <<= 1) {
                float ov = __shfl_xor(bestv, off);
                int oc = __shfl_xor(bestc, off);
                if (ov > bestv || (ov == bestv && oc < bestc)) { bestv = ov; bestc = oc; }
            }
            if (valid && r16 == 0) {
                uint u = __builtin_bit_cast(uint, bestv);
                u = (u & 0x80000000u) ? ~u : (u | 0x80000000u);
                keys[(long)gr * 512 + nt * 2 + wc] = (((ull)u) << 32) | (ull)(65535 - bestc);
            }
        }
    }
}

// ---------------- k_argmax2: reduce 500 per-tile keys per row ----------------
__global__ __launch_bounds__(256) void k_argmax2(const ull* __restrict__ keys, float* __restrict__ pred) {
    int r = blockIdx.x, tid = threadIdx.x;
    ull best = 0;
    for (int j = tid; j < 500; j += 256) {
        ull k = keys[(long)r * 512 + j];
        if (k > best) best = k;
    }
    __shared__ ull sk[256];
    sk[tid] = best;
    __syncthreads();
    for (int s = 128; s > 0; s >>= 1) {
        if (tid < s) { if (sk[tid + s] > sk[tid]) sk[tid] = sk[tid + s]; }
        __syncthreads();
    }
    if (tid == 0) pred[r] = (float)(65535 - (int)(sk[0] & 0xFFFFull));
}

// ---------------- host ----------------
extern "C" void kernel_launch(void* const* d_in, const int* in_sizes, int n_in,
                              void* d_out, int out_size, void* d_ws, size_t ws_size,
                              hipStream_t stream) {
    const int*   tok  = (const int*)d_in[0];
    const float* enc  = (const float*)d_in[1];
    const float* h0   = (const float*)d_in[2];
    const float* c0   = (const float*)d_in[3];
    const float* emb  = (const float*)d_in[6];
    const float* Wih  = (const float*)d_in[7];
    const float* Whh  = (const float*)d_in[8];
    const float* bih  = (const float*)d_in[9];
    const float* bhh  = (const float*)d_in[10];
    const float* Wht  = (const float*)d_in[11];
    const float* bht  = (const float*)d_in[12];
    const float* Wvoc = (const float*)d_in[13];
    const float* bvoc = (const float*)d_in[14];
    float* out = (float*)d_out;

    float* gates_x = (float*)d_ws;
    float* gate_h  = gates_x + NF_GX;
    float* hxT     = gate_h + NF_GH;
    float* ctxT    = hxT + NF_V32;
    float* cx      = ctxT + NF_V32;
    ushort* hxa_hi = (ushort*)(cx + NF_V32);
    ushort* hxa_lo = hxa_hi + (long)Mp * Hz;
    ull*    keys   = (ull*)(hxa_lo + (long)Mp * Hz);

    k_pre<<<512, 256, 0, stream>>>(hxT, cx, hxa_hi, hxa_lo, h0, c0);
    k_xgemm<<<13 * 32, 256, 0, stream>>>(emb, tok, Wih, bih, bhh, gates_x);

    void* args[] = { &gates_x, &gate_h, &hxT, &ctxT, &cx, &hxa_hi, &hxa_lo,
                     (void*)&Whh, (void*)&Wht, (void*)&enc, (void*)&bht };
    hipLaunchCooperativeKernel((const void*)k_rec, dim3(256), dim3(512), args, 0, stream);

    k_voc2<<<13 * 250, 256, 0, stream>>>(hxa_hi, hxa_lo, Wvoc, bvoc, out, keys);
    k_argmax2<<<1600, 256, 0, stream>>>(keys, out + (long)Mz * Vz);
}

// Round 3
// 1894.727 us; speedup vs baseline: 4.0376x; 4.0376x over previous
//
#include <hip/hip_runtime.h>
#include <math.h>

typedef short bf16x8 __attribute__((ext_vector_type(8)));
typedef float f32x4 __attribute__((ext_vector_type(4)));
typedef unsigned long long ull;
typedef unsigned int uint;
typedef unsigned short ushort;

#define Bz 32
#define Tz 50
#define Sz 40
#define Vz 32000
#define Dz 512
#define Hz 1024
#define Mz 1600
#define Mp 1664

__device__ __forceinline__ ushort f2bf(float f) {
    uint u = __builtin_bit_cast(uint, f);
    return (ushort)((u + 0x7FFFu + ((u >> 16) & 1u)) >> 16);
}
__device__ __forceinline__ float bf2f(ushort h) {
    uint u = ((uint)h) << 16;
    return __builtin_bit_cast(float, u);
}
__device__ __forceinline__ float sigf(float x) { return 1.f / (1.f + expf(-x)); }

// ---------- k_pre: init hx(-1)/cx, zero AH pad rows ----------
__global__ __launch_bounds__(256) void k_pre(float* hxf, ushort* hxA_hi, ushort* hxA_lo,
                                             float* cx, ushort* AH_hi, ushort* AH_lo,
                                             const float* h0, const float* c0) {
    int gid = blockIdx.x * 256 + threadIdx.x;
    if (gid < 32768) {
        float v = h0[gid];
        hxf[gid] = v;                      // buffer 0
        ushort hi = f2bf(v);
        hxA_hi[gid] = hi;
        hxA_lo[gid] = f2bf(v - bf2f(hi));
    } else if (gid < 65536) {
        cx[gid - 32768] = c0[gid - 32768];
    } else {
        int g = gid - 65536;               // [0, 131072): pad rows 1600..1663
        AH_hi[(long)Mz * 2048 + g] = 0;
        AH_lo[(long)Mz * 2048 + g] = 0;
    }
}

// ---------- k_xgemm: gates_x = emb[tok] @ Wih^T + bih + bhh (split-bf16 MFMA) ----------
__global__ __launch_bounds__(256, 1) void k_xgemm(const float* __restrict__ emb,
                                                  const int* __restrict__ tok,
                                                  const float* __restrict__ Wih,
                                                  const float* __restrict__ bih,
                                                  const float* __restrict__ bhh,
                                                  float* __restrict__ gx) {
    __shared__ ushort sAh[128][40];
    __shared__ ushort sAl[128][40];
    __shared__ ushort sBh[128][40];
    __shared__ ushort sBl[128][40];
    int bid = blockIdx.x;
    int mt = bid >> 5, nt = bid & 31;
    int tid = threadIdx.x;
    int row = tid >> 1, half = tid & 1;
    int wv = tid >> 6, lane = tid & 63;
    int wr = wv >> 1, wc = wv & 1;
    int m0 = wr * 64, n0 = wc * 64;
    int r16 = lane & 15, kg = lane >> 4, k0 = kg * 8;

    f32x4 acc[4][4];
#pragma unroll
    for (int i = 0; i < 4; i++)
#pragma unroll
        for (int j = 0; j < 4; j++) acc[i][j] = (f32x4){0.f, 0.f, 0.f, 0.f};

    int r = mt * 128 + row;
    int tk = (r < Mz) ? tok[r] : 0;
    const float* arow = emb + (long)tk * Dz;
    const float* brow = Wih + (long)(nt * 128 + row) * Dz;

    for (int kb = 0; kb < Dz; kb += 32) {
        {
            ushort hh[16], ll[16];
#pragma unroll
            for (int q = 0; q < 16; q += 4) {
                float4 w4 = (r < Mz) ? *(const float4*)(arow + kb + half * 16 + q)
                                     : (float4){0.f, 0.f, 0.f, 0.f};
                float vv[4] = {w4.x, w4.y, w4.z, w4.w};
#pragma unroll
                for (int e = 0; e < 4; ++e) {
                    ushort h_ = f2bf(vv[e]);
                    hh[q + e] = h_;
                    ll[q + e] = f2bf(vv[e] - bf2f(h_));
                }
            }
            *(uint4*)&sAh[row][half * 16]     = *(uint4*)&hh[0];
            *(uint4*)&sAh[row][half * 16 + 8] = *(uint4*)&hh[8];
            *(uint4*)&sAl[row][half * 16]     = *(uint4*)&ll[0];
            *(uint4*)&sAl[row][half * 16 + 8] = *(uint4*)&ll[8];
        }
        {
            ushort hh[16], ll[16];
#pragma unroll
            for (int q = 0; q < 16; q += 4) {
                float4 w4 = *(const float4*)(brow + kb + half * 16 + q);
                float vv[4] = {w4.x, w4.y, w4.z, w4.w};
#pragma unroll
                for (int e = 0; e < 4; ++e) {
                    ushort h_ = f2bf(vv[e]);
                    hh[q + e] = h_;
                    ll[q + e] = f2bf(vv[e] - bf2f(h_));
                }
            }
            *(uint4*)&sBh[row][half * 16]     = *(uint4*)&hh[0];
            *(uint4*)&sBh[row][half * 16 + 8] = *(uint4*)&hh[8];
            *(uint4*)&sBl[row][half * 16]     = *(uint4*)&ll[0];
            *(uint4*)&sBl[row][half * 16 + 8] = *(uint4*)&ll[8];
        }
        __syncthreads();
        bf16x8 af[4], alf[4], bhf[4], blf[4];
#pragma unroll
        for (int i = 0; i < 4; ++i) {
            af[i]  = *(const bf16x8*)&sAh[m0 + i * 16 + r16][k0];
            alf[i] = *(const bf16x8*)&sAl[m0 + i * 16 + r16][k0];
            bhf[i] = *(const bf16x8*)&sBh[n0 + i * 16 + r16][k0];
            blf[i] = *(const bf16x8*)&sBl[n0 + i * 16 + r16][k0];
        }
#pragma unroll
        for (int i = 0; i < 4; ++i)
#pragma unroll
            for (int jn = 0; jn < 4; ++jn) {
                acc[i][jn] = __builtin_amdgcn_mfma_f32_16x16x32_bf16(af[i],  bhf[jn], acc[i][jn], 0, 0, 0);
                acc[i][jn] = __builtin_amdgcn_mfma_f32_16x16x32_bf16(af[i],  blf[jn], acc[i][jn], 0, 0, 0);
                acc[i][jn] = __builtin_amdgcn_mfma_f32_16x16x32_bf16(alf[i], bhf[jn], acc[i][jn], 0, 0, 0);
            }
        __syncthreads();
    }
#pragma unroll
    for (int i = 0; i < 4; ++i) {
        int gr0 = mt * 128 + m0 + i * 16 + kg * 4;
#pragma unroll
        for (int reg = 0; reg < 4; ++reg) {
            int gr = gr0 + reg;
            if (gr >= Mz) continue;
#pragma unroll
            for (int jn = 0; jn < 4; ++jn) {
                int gc = nt * 128 + n0 + jn * 16 + r16;
                gx[(long)gr * 4096 + gc] = acc[i][jn][reg] + bih[gc] + bhh[gc];
            }
        }
    }
}

// ---------- k_step: gates MFMA + cell (WG 0..63) || attention t-1 (WG 64..95) ----------
__global__ __launch_bounds__(256) void k_step(
    const float* __restrict__ gx, const float* __restrict__ Whh,
    ushort* __restrict__ hxA_hi, ushort* __restrict__ hxA_lo,
    float* __restrict__ hxf, float* __restrict__ cx,
    ushort* __restrict__ AH_hi, ushort* __restrict__ AH_lo,
    const float* __restrict__ enc, int t, int do_gates, int do_attn) {
    __shared__ float sg[4][32][16];
    __shared__ float hxs[Hz];
    __shared__ float sc[64];
    __shared__ float aw[Sz];
    int wid = blockIdx.x, tid = threadIdx.x;
    int p = t & 1, q = p ^ 1;

    if (wid < 64) {
        if (!do_gates) return;
        int w = wid;
        int v = tid >> 6, lane = tid & 63;
        int r16 = lane & 15, kg = lane >> 4;
        const ushort* Ah = hxA_hi + p * 32768;
        const ushort* Al = hxA_lo + p * 32768;
        int j = v * 1024 + w * 16 + r16;         // this lane's Whh row (gate v)
        const float* wrow = Whh + (long)j * Hz;
        f32x4 acc0 = {0.f, 0.f, 0.f, 0.f}, acc1 = {0.f, 0.f, 0.f, 0.f};
#pragma unroll 2
        for (int kb = 0; kb < Hz; kb += 32) {
            int k0 = kb + kg * 8;
            bf16x8 a_h0 = *(const bf16x8*)(Ah + r16 * Hz + k0);
            bf16x8 a_h1 = *(const bf16x8*)(Ah + (16 + r16) * Hz + k0);
            bf16x8 a_l0 = *(const bf16x8*)(Al + r16 * Hz + k0);
            bf16x8 a_l1 = *(const bf16x8*)(Al + (16 + r16) * Hz + k0);
            float4 w0 = *(const float4*)(wrow + k0);
            float4 w1 = *(const float4*)(wrow + k0 + 4);
            float wf[8] = {w0.x, w0.y, w0.z, w0.w, w1.x, w1.y, w1.z, w1.w};
            bf16x8 b_h, b_l;
#pragma unroll
            for (int e = 0; e < 8; ++e) {
                ushort hi = f2bf(wf[e]);
                b_h[e] = (short)hi;
                b_l[e] = (short)f2bf(wf[e] - bf2f(hi));
            }
            acc0 = __builtin_amdgcn_mfma_f32_16x16x32_bf16(a_h0, b_h, acc0, 0, 0, 0);
            acc0 = __builtin_amdgcn_mfma_f32_16x16x32_bf16(a_h0, b_l, acc0, 0, 0, 0);
            acc0 = __builtin_amdgcn_mfma_f32_16x16x32_bf16(a_l0, b_h, acc0, 0, 0, 0);
            acc1 = __builtin_amdgcn_mfma_f32_16x16x32_bf16(a_h1, b_h, acc1, 0, 0, 0);
            acc1 = __builtin_amdgcn_mfma_f32_16x16x32_bf16(a_h1, b_l, acc1, 0, 0, 0);
            acc1 = __builtin_amdgcn_mfma_f32_16x16x32_bf16(a_l1, b_h, acc1, 0, 0, 0);
        }
        // exchange gates through LDS (wave v holds gate v: C row=b, col=h)
#pragma unroll
        for (int i = 0; i < 2; ++i) {
            f32x4 a = (i == 0) ? acc0 : acc1;
#pragma unroll
            for (int reg = 0; reg < 4; ++reg) {
                int b = i * 16 + kg * 4 + reg;
                sg[v][b][r16] = a[reg] + gx[((long)b * Tz + t) * 4096 + v * 1024 + w * 16 + r16];
            }
        }
        __syncthreads();
#pragma unroll
        for (int u = 0; u < 2; ++u) {
            int pidx = tid * 2 + u;
            int b = pidx >> 4, h = pidx & 15;
            int hg = w * 16 + h;
            float ig = sigf(sg[0][b][h]), fg = sigf(sg[1][b][h]);
            float gg = tanhf(sg[2][b][h]), og = sigf(sg[3][b][h]);
            long ci = (long)b * Hz + hg;
            float c = fg * cx[ci] + ig * gg;
            float hv = og * tanhf(c);
            cx[ci] = c;
            hxf[q * 32768 + ci] = hv;
            ushort hi = f2bf(hv);
            hxA_hi[q * 32768 + ci] = hi;
            hxA_lo[q * 32768 + ci] = f2bf(hv - bf2f(hi));
        }
    } else {
        if (!do_attn) return;
        int b = wid - 64;
        const float* hsrc = hxf + p * 32768 + (long)b * Hz;
        *(float4*)&hxs[tid * 4] = *(const float4*)(hsrc + tid * 4);
        __syncthreads();
        int wv = tid >> 6, lane = tid & 63;
        float hreg[16];
#pragma unroll
        for (int u = 0; u < 16; ++u) hreg[u] = hxs[lane * 16 + u];
        const float* eb = enc + (long)b * Sz * Hz;
        for (int s = wv; s < Sz; s += 4) {
            const float* er = eb + (long)s * Hz + lane * 16;
            float sum = 0.f;
#pragma unroll
            for (int qq = 0; qq < 4; ++qq) {
                float4 e4 = *(const float4*)(er + qq * 4);
                sum += e4.x * hreg[qq*4] + e4.y * hreg[qq*4+1] + e4.z * hreg[qq*4+2] + e4.w * hreg[qq*4+3];
            }
#pragma unroll
            for (int off = 32; off >= 1; off >>= 1) sum += __shfl_xor(sum, off);
            if (lane == 0) sc[s] = sum;
        }
        __syncthreads();
        if (tid < 64) {
            float vv = (tid < Sz) ? sc[tid] : -3.402823e38f;
            float mx = vv;
#pragma unroll
            for (int off = 32; off >= 1; off >>= 1) mx = fmaxf(mx, __shfl_xor(mx, off));
            float e = (tid < Sz) ? expf(vv - mx) : 0.f;
            float ssum = e;
#pragma unroll
            for (int off = 32; off >= 1; off >>= 1) ssum += __shfl_xor(ssum, off);
            if (tid < Sz) aw[tid] = e / ssum;
        }
        __syncthreads();
        float c4[4] = {0.f, 0.f, 0.f, 0.f};
        for (int s = 0; s < Sz; ++s) {
            float4 e4 = *(const float4*)(eb + (long)s * Hz + tid * 4);
            float a = aw[s];
            c4[0] += a * e4.x; c4[1] += a * e4.y; c4[2] += a * e4.z; c4[3] += a * e4.w;
        }
        long r = (long)b * Tz + (t - 1);
        ushort* dh = AH_hi + r * 2048;
        ushort* dl = AH_lo + r * 2048;
#pragma unroll
        for (int u = 0; u < 4; ++u) {
            ushort hi = f2bf(c4[u]);
            dh[tid * 4 + u] = hi;
            dl[tid * 4 + u] = f2bf(c4[u] - bf2f(hi));
            float hvv = hxs[tid * 4 + u];
            ushort hi2 = f2bf(hvv);
            dh[1024 + tid * 4 + u] = hi2;
            dl[1024 + tid * 4 + u] = f2bf(hvv - bf2f(hi2));
        }
    }
}

// ---------- k_ht: HXA = tanh(AH @ Wht^T + bht), bf16 hi/lo out ----------
__global__ __launch_bounds__(256, 1) void k_ht(const ushort* __restrict__ Ah,
                                               const ushort* __restrict__ Al,
                                               const float* __restrict__ Wht,
                                               const float* __restrict__ bht,
                                               ushort* __restrict__ Hh, ushort* __restrict__ Hl) {
    __shared__ ushort sAh[128][40];
    __shared__ ushort sAl[128][40];
    __shared__ ushort sBh[128][40];
    __shared__ ushort sBl[128][40];
    int bid = blockIdx.x;
    int mt = bid >> 3, nt = bid & 7;
    int tid = threadIdx.x;
    int row = tid >> 1, half = tid & 1;
    int wv = tid >> 6, lane = tid & 63;
    int wr = wv >> 1, wc = wv & 1;
    int m0 = wr * 64, n0 = wc * 64;
    int r16 = lane & 15, kg = lane >> 4, k0 = kg * 8;

    f32x4 acc[4][4];
#pragma unroll
    for (int i = 0; i < 4; i++)
#pragma unroll
        for (int j = 0; j < 4; j++) acc[i][j] = (f32x4){0.f, 0.f, 0.f, 0.f};

    long arow = (long)(mt * 128 + row) * 2048;
    const float* brow = Wht + (long)(nt * 128 + row) * 2048;

    for (int kb = 0; kb < 2048; kb += 32) {
        const ushort* pa = Ah + arow + kb + half * 16;
        *(uint4*)&sAh[row][half * 16]     = *(const uint4*)pa;
        *(uint4*)&sAh[row][half * 16 + 8] = *(const uint4*)(pa + 8);
        const ushort* pl = Al + arow + kb + half * 16;
        *(uint4*)&sAl[row][half * 16]     = *(const uint4*)pl;
        *(uint4*)&sAl[row][half * 16 + 8] = *(const uint4*)(pl + 8);
        {
            ushort hh[16], ll[16];
#pragma unroll
            for (int qq = 0; qq < 16; qq += 4) {
                float4 w4 = *(const float4*)(brow + kb + half * 16 + qq);
                float vv[4] = {w4.x, w4.y, w4.z, w4.w};
#pragma unroll
                for (int e = 0; e < 4; ++e) {
                    ushort h_ = f2bf(vv[e]);
                    hh[qq + e] = h_;
                    ll[qq + e] = f2bf(vv[e] - bf2f(h_));
                }
            }
            *(uint4*)&sBh[row][half * 16]     = *(uint4*)&hh[0];
            *(uint4*)&sBh[row][half * 16 + 8] = *(uint4*)&hh[8];
            *(uint4*)&sBl[row][half * 16]     = *(uint4*)&ll[0];
            *(uint4*)&sBl[row][half * 16 + 8] = *(uint4*)&ll[8];
        }
        __syncthreads();
        bf16x8 af[4], alf[4], bhf[4], blf[4];
#pragma unroll
        for (int i = 0; i < 4; ++i) {
            af[i]  = *(const bf16x8*)&sAh[m0 + i * 16 + r16][k0];
            alf[i] = *(const bf16x8*)&sAl[m0 + i * 16 + r16][k0];
            bhf[i] = *(const bf16x8*)&sBh[n0 + i * 16 + r16][k0];
            blf[i] = *(const bf16x8*)&sBl[n0 + i * 16 + r16][k0];
        }
#pragma unroll
        for (int i = 0; i < 4; ++i)
#pragma unroll
            for (int jn = 0; jn < 4; ++jn) {
                acc[i][jn] = __builtin_amdgcn_mfma_f32_16x16x32_bf16(af[i],  bhf[jn], acc[i][jn], 0, 0, 0);
                acc[i][jn] = __builtin_amdgcn_mfma_f32_16x16x32_bf16(af[i],  blf[jn], acc[i][jn], 0, 0, 0);
                acc[i][jn] = __builtin_amdgcn_mfma_f32_16x16x32_bf16(alf[i], bhf[jn], acc[i][jn], 0, 0, 0);
            }
        __syncthreads();
    }
#pragma unroll
    for (int i = 0; i < 4; ++i) {
        int gr0 = mt * 128 + m0 + i * 16 + kg * 4;
#pragma unroll
        for (int reg = 0; reg < 4; ++reg) {
            int gr = gr0 + reg;
            bool valid = gr < Mz;
#pragma unroll
            for (int jn = 0; jn < 4; ++jn) {
                int gc = nt * 128 + n0 + jn * 16 + r16;
                float vv = tanhf(acc[i][jn][reg] + bht[gc]);
                ushort hi = 0, lo = 0;
                if (valid) { hi = f2bf(vv); lo = f2bf(vv - bf2f(hi)); }
                Hh[(long)gr * Hz + gc] = hi;
                Hl[(long)gr * Hz + gc] = lo;
            }
        }
    }
}

// ---------- k_voc2: logits GEMM (split-bf16 MFMA) + fused per-tile argmax keys ----------
__global__ __launch_bounds__(256, 1) void k_voc2(
    const ushort* __restrict__ Ah, const ushort* __restrict__ Al,
    const float* __restrict__ W, const float* __restrict__ bvoc,
    float* __restrict__ out, ull* __restrict__ keys) {
    __shared__ ushort sAh[128][40];
    __shared__ ushort sAl[128][40];
    __shared__ ushort sBh[128][40];
    __shared__ ushort sBl[128][40];
    int bid = blockIdx.x;
    int mt = bid / 250, nt = bid % 250;
    int tid = threadIdx.x;
    int row = tid >> 1, half = tid & 1;
    int wv = tid >> 6, lane = tid & 63;
    int wr = wv >> 1, wc = wv & 1;
    int m0 = wr * 64, n0 = wc * 64;
    int r16 = lane & 15, kg = lane >> 4, k0 = kg * 8;

    f32x4 acc[4][4];
#pragma unroll
    for (int i = 0; i < 4; i++)
#pragma unroll
        for (int j = 0; j < 4; j++) acc[i][j] = (f32x4){0.f, 0.f, 0.f, 0.f};

    long arow = (long)(mt * 128 + row) * Hz;
    long wrow = (long)(nt * 128 + row) * Hz;

    for (int kb = 0; kb < Hz; kb += 32) {
        const ushort* pa = Ah + arow + kb + half * 16;
        *(uint4*)&sAh[row][half * 16]     = *(const uint4*)pa;
        *(uint4*)&sAh[row][half * 16 + 8] = *(const uint4*)(pa + 8);
        const ushort* pl = Al + arow + kb + half * 16;
        *(uint4*)&sAl[row][half * 16]     = *(const uint4*)pl;
        *(uint4*)&sAl[row][half * 16 + 8] = *(const uint4*)(pl + 8);
        {
            const float* pw = W + wrow + kb + half * 16;
            ushort hh[16], ll[16];
#pragma unroll
            for (int qq = 0; qq < 16; qq += 4) {
                float4 w4 = *(const float4*)(pw + qq);
                float vv[4] = {w4.x, w4.y, w4.z, w4.w};
#pragma unroll
                for (int e = 0; e < 4; ++e) {
                    ushort h_ = f2bf(vv[e]);
                    hh[qq + e] = h_;
                    ll[qq + e] = f2bf(vv[e] - bf2f(h_));
                }
            }
            *(uint4*)&sBh[row][half * 16]     = *(uint4*)&hh[0];
            *(uint4*)&sBh[row][half * 16 + 8] = *(uint4*)&hh[8];
            *(uint4*)&sBl[row][half * 16]     = *(uint4*)&ll[0];
            *(uint4*)&sBl[row][half * 16 + 8] = *(uint4*)&ll[8];
        }
        __syncthreads();
        bf16x8 af[4], alf[4], bhf[4], blf[4];
#pragma unroll
        for (int i = 0; i < 4; ++i) {
            af[i]  = *(const bf16x8*)&sAh[m0 + i * 16 + r16][k0];
            alf[i] = *(const bf16x8*)&sAl[m0 + i * 16 + r16][k0];
            bhf[i] = *(const bf16x8*)&sBh[n0 + i * 16 + r16][k0];
            blf[i] = *(const bf16x8*)&sBl[n0 + i * 16 + r16][k0];
        }
#pragma unroll
        for (int i = 0; i < 4; ++i)
#pragma unroll
            for (int jn = 0; jn < 4; ++jn) {
                acc[i][jn] = __builtin_amdgcn_mfma_f32_16x16x32_bf16(af[i],  bhf[jn], acc[i][jn], 0, 0, 0);
                acc[i][jn] = __builtin_amdgcn_mfma_f32_16x16x32_bf16(af[i],  blf[jn], acc[i][jn], 0, 0, 0);
                acc[i][jn] = __builtin_amdgcn_mfma_f32_16x16x32_bf16(alf[i], bhf[jn], acc[i][jn], 0, 0, 0);
            }
        __syncthreads();
    }
#pragma unroll
    for (int i = 0; i < 4; ++i) {
        int gr0 = mt * 128 + m0 + i * 16 + kg * 4;
#pragma unroll
        for (int reg = 0; reg < 4; ++reg) {
            int gr = gr0 + reg;
            bool valid = gr < Mz;
            float bestv = -3.402823e38f;
            int bestc = 0;
#pragma unroll
            for (int jn = 0; jn < 4; ++jn) {
                int gc = nt * 128 + n0 + jn * 16 + r16;
                float v = acc[i][jn][reg] + bvoc[gc];
                if (valid) out[(long)gr * Vz + gc] = v;
                if (v > bestv) { bestv = v; bestc = gc; }
            }
#pragma unroll
            for (int off = 1; off < 16; off <<= 1) {
                float ov = __shfl_xor(bestv, off);
                int oc = __shfl_xor(bestc, off);
                if (ov > bestv || (ov == bestv && oc < bestc)) { bestv = ov; bestc = oc; }
            }
            if (valid && r16 == 0) {
                uint u = __builtin_bit_cast(uint, bestv);
                u = (u & 0x80000000u) ? ~u : (u | 0x80000000u);
                keys[(long)gr * 512 + nt * 2 + wc] = (((ull)u) << 32) | (ull)(65535 - bestc);
            }
        }
    }
}

__global__ __launch_bounds__(256) void k_argmax2(const ull* __restrict__ keys, float* __restrict__ pred) {
    int r = blockIdx.x, tid = threadIdx.x;
    ull best = 0;
    for (int j = tid; j < 500; j += 256) {
        ull k = keys[(long)r * 512 + j];
        if (k > best) best = k;
    }
    __shared__ ull sk[256];
    sk[tid] = best;
    __syncthreads();
    for (int s = 128; s > 0; s >>= 1) {
        if (tid < s) { if (sk[tid + s] > sk[tid]) sk[tid] = sk[tid + s]; }
        __syncthreads();
    }
    if (tid == 0) pred[r] = (float)(65535 - (int)(sk[0] & 0xFFFFull));
}

// ---------------- host ----------------
extern "C" void kernel_launch(void* const* d_in, const int* in_sizes, int n_in,
                              void* d_out, int out_size, void* d_ws, size_t ws_size,
                              hipStream_t stream) {
    const int*   tok  = (const int*)d_in[0];
    const float* enc  = (const float*)d_in[1];
    const float* h0   = (const float*)d_in[2];
    const float* c0   = (const float*)d_in[3];
    const float* emb  = (const float*)d_in[6];
    const float* Wih  = (const float*)d_in[7];
    const float* Whh  = (const float*)d_in[8];
    const float* bih  = (const float*)d_in[9];
    const float* bhh  = (const float*)d_in[10];
    const float* Wht  = (const float*)d_in[11];
    const float* bht  = (const float*)d_in[12];
    const float* Wvoc = (const float*)d_in[13];
    const float* bvoc = (const float*)d_in[14];
    float* out = (float*)d_out;

    float*  gx      = (float*)d_ws;                          // [1600][4096]
    ushort* hxA_hi  = (ushort*)(gx + (long)Mz * 4096);       // [2][32768]
    ushort* hxA_lo  = hxA_hi + 2 * 32768;
    float*  hxf     = (float*)(hxA_lo + 2 * 32768);          // [2][32768]
    float*  cx      = hxf + 2 * 32768;                       // [32768]
    ushort* AH_hi   = (ushort*)(cx + 32768);                 // [1664][2048]
    ushort* AH_lo   = AH_hi + (long)Mp * 2048;
    ushort* HXA_hi  = AH_lo + (long)Mp * 2048;               // [1664][1024]
    ushort* HXA_lo  = HXA_hi + (long)Mp * 1024;
    ull*    keys    = (ull*)(HXA_lo + (long)Mp * 1024);      // [1600][512]

    k_pre<<<768, 256, 0, stream>>>(hxf, hxA_hi, hxA_lo, cx, AH_hi, AH_lo, h0, c0);
    k_xgemm<<<13 * 32, 256, 0, stream>>>(emb, tok, Wih, bih, bhh, gx);
    for (int t = 0; t <= Tz; ++t) {
        k_step<<<96, 256, 0, stream>>>(gx, Whh, hxA_hi, hxA_lo, hxf, cx, AH_hi, AH_lo,
                                       enc, t, (t < Tz) ? 1 : 0, (t > 0) ? 1 : 0);
    }
    k_ht<<<13 * 8, 256, 0, stream>>>(AH_hi, AH_lo, Wht, bht, HXA_hi, HXA_lo);
    k_voc2<<<13 * 250, 256, 0, stream>>>(HXA_hi, HXA_lo, Wvoc, bvoc, out, keys);
    k_argmax2<<<1600, 256, 0, stream>>>(keys, out + (long)Mz * Vz);
}

// Round 4
// 1788.371 us; speedup vs baseline: 4.2777x; 1.0595x over previous
//
#include <hip/hip_runtime.h>
#include <math.h>

typedef short bf16x8 __attribute__((ext_vector_type(8)));
typedef float f32x4 __attribute__((ext_vector_type(4)));
typedef unsigned long long ull;
typedef unsigned int uint;
typedef unsigned short ushort;

#define Bz 32
#define Tz 50
#define Sz 40
#define Vz 32000
#define Dz 512
#define Hz 1024
#define Mz 1600
#define Mp 1664

__device__ __forceinline__ ushort f2bf(float f) {           // round-to-nearest
    uint u = __builtin_bit_cast(uint, f);
    return (ushort)((u + 0x7FFFu + ((u >> 16) & 1u)) >> 16);
}
__device__ __forceinline__ float bf2f(ushort h) {
    uint u = ((uint)h) << 16;
    return __builtin_bit_cast(float, u);
}
// cheap truncation split: f = hi + rem, |rem| <= 2^-8 |f|
__device__ __forceinline__ void splitf(float f, ushort& hi, ushort& lo) {
    uint u = __builtin_bit_cast(uint, f);
    hi = (ushort)(u >> 16);
    float rem = f - __builtin_bit_cast(float, u & 0xFFFF0000u);
    lo = (ushort)(__builtin_bit_cast(uint, rem) >> 16);
}
__device__ __forceinline__ float sigf(float x) { return 1.f / (1.f + expf(-x)); }

// ---------- k_pre: init hxA[0] hi/lo from h0, cx; zero AH pad rows ----------
__global__ __launch_bounds__(256) void k_pre(ushort* hxA_hi, ushort* hxA_lo, float* cx,
                                             ushort* AH_hi, ushort* AH_lo,
                                             const float* h0, const float* c0) {
    int gid = blockIdx.x * 256 + threadIdx.x;
    if (gid < 32768) {
        float v = h0[gid];
        ushort hi, lo;
        splitf(v, hi, lo);
        hxA_hi[gid] = hi;
        hxA_lo[gid] = lo;
    } else if (gid < 65536) {
        cx[gid - 32768] = c0[gid - 32768];
    } else {
        int g = gid - 65536;               // [0, 131072): AH pad rows 1600..1663
        AH_hi[(long)Mz * 2048 + g] = 0;
        AH_lo[(long)Mz * 2048 + g] = 0;
    }
}

// ---------- k_wsplit: fp32 matrix -> bf16 hi/lo planes ----------
__global__ __launch_bounds__(256) void k_wsplit(const float* __restrict__ src,
                                                ushort* __restrict__ hi, ushort* __restrict__ lo,
                                                int n4) {
    int stride = gridDim.x * 256;
    for (int i = blockIdx.x * 256 + threadIdx.x; i < n4; i += stride) {
        float4 f = *(const float4*)(src + (long)i * 4);
        float vv[4] = {f.x, f.y, f.z, f.w};
        ushort h[4], l[4];
#pragma unroll
        for (int e = 0; e < 4; ++e) splitf(vv[e], h[e], l[e]);
        uint2 hp, lp;
        hp.x = (uint)h[0] | ((uint)h[1] << 16);
        hp.y = (uint)h[2] | ((uint)h[3] << 16);
        lp.x = (uint)l[0] | ((uint)l[1] << 16);
        lp.y = (uint)l[2] | ((uint)l[3] << 16);
        *(uint2*)(hi + (long)i * 4) = hp;
        *(uint2*)(lo + (long)i * 4) = lp;
    }
}

// ---------- k_xgemm: gates_x = emb[tok] @ Wih^T + bih + bhh (split-bf16 MFMA) ----------
__global__ __launch_bounds__(256, 1) void k_xgemm(const float* __restrict__ emb,
                                                  const int* __restrict__ tok,
                                                  const float* __restrict__ Wih,
                                                  const float* __restrict__ bih,
                                                  const float* __restrict__ bhh,
                                                  float* __restrict__ gx) {
    __shared__ ushort sAh[128][40];
    __shared__ ushort sAl[128][40];
    __shared__ ushort sBh[128][40];
    __shared__ ushort sBl[128][40];
    int bid = blockIdx.x;
    int mt = bid >> 5, nt = bid & 31;
    int tid = threadIdx.x;
    int row = tid >> 1, half = tid & 1;
    int wv = tid >> 6, lane = tid & 63;
    int wr = wv >> 1, wc = wv & 1;
    int m0 = wr * 64, n0 = wc * 64;
    int r16 = lane & 15, kg = lane >> 4, k0 = kg * 8;

    f32x4 acc[4][4];
#pragma unroll
    for (int i = 0; i < 4; i++)
#pragma unroll
        for (int j = 0; j < 4; j++) acc[i][j] = (f32x4){0.f, 0.f, 0.f, 0.f};

    int r = mt * 128 + row;
    int tk = (r < Mz) ? tok[r] : 0;
    const float* arow = emb + (long)tk * Dz;
    const float* brow = Wih + (long)(nt * 128 + row) * Dz;

    for (int kb = 0; kb < Dz; kb += 32) {
        {
            ushort hh[16], ll[16];
#pragma unroll
            for (int q = 0; q < 16; q += 4) {
                float4 w4 = (r < Mz) ? *(const float4*)(arow + kb + half * 16 + q)
                                     : (float4){0.f, 0.f, 0.f, 0.f};
                float vv[4] = {w4.x, w4.y, w4.z, w4.w};
#pragma unroll
                for (int e = 0; e < 4; ++e) splitf(vv[e], hh[q + e], ll[q + e]);
            }
            *(uint4*)&sAh[row][half * 16]     = *(uint4*)&hh[0];
            *(uint4*)&sAh[row][half * 16 + 8] = *(uint4*)&hh[8];
            *(uint4*)&sAl[row][half * 16]     = *(uint4*)&ll[0];
            *(uint4*)&sAl[row][half * 16 + 8] = *(uint4*)&ll[8];
        }
        {
            ushort hh[16], ll[16];
#pragma unroll
            for (int q = 0; q < 16; q += 4) {
                float4 w4 = *(const float4*)(brow + kb + half * 16 + q);
                float vv[4] = {w4.x, w4.y, w4.z, w4.w};
#pragma unroll
                for (int e = 0; e < 4; ++e) splitf(vv[e], hh[q + e], ll[q + e]);
            }
            *(uint4*)&sBh[row][half * 16]     = *(uint4*)&hh[0];
            *(uint4*)&sBh[row][half * 16 + 8] = *(uint4*)&hh[8];
            *(uint4*)&sBl[row][half * 16]     = *(uint4*)&ll[0];
            *(uint4*)&sBl[row][half * 16 + 8] = *(uint4*)&ll[8];
        }
        __syncthreads();
        bf16x8 af[4], alf[4], bhf[4], blf[4];
#pragma unroll
        for (int i = 0; i < 4; ++i) {
            af[i]  = *(const bf16x8*)&sAh[m0 + i * 16 + r16][k0];
            alf[i] = *(const bf16x8*)&sAl[m0 + i * 16 + r16][k0];
            bhf[i] = *(const bf16x8*)&sBh[n0 + i * 16 + r16][k0];
            blf[i] = *(const bf16x8*)&sBl[n0 + i * 16 + r16][k0];
        }
#pragma unroll
        for (int i = 0; i < 4; ++i)
#pragma unroll
            for (int jn = 0; jn < 4; ++jn) {
                acc[i][jn] = __builtin_amdgcn_mfma_f32_16x16x32_bf16(af[i],  bhf[jn], acc[i][jn], 0, 0, 0);
                acc[i][jn] = __builtin_amdgcn_mfma_f32_16x16x32_bf16(af[i],  blf[jn], acc[i][jn], 0, 0, 0);
                acc[i][jn] = __builtin_amdgcn_mfma_f32_16x16x32_bf16(alf[i], bhf[jn], acc[i][jn], 0, 0, 0);
            }
        __syncthreads();
    }
#pragma unroll
    for (int i = 0; i < 4; ++i) {
        int gr0 = mt * 128 + m0 + i * 16 + kg * 4;
#pragma unroll
        for (int reg = 0; reg < 4; ++reg) {
            int gr = gr0 + reg;
            if (gr >= Mz) continue;
#pragma unroll
            for (int jn = 0; jn < 4; ++jn) {
                int gc = nt * 128 + n0 + jn * 16 + r16;
                gx[(long)gr * 4096 + gc] = acc[i][jn][reg] + bih[gc] + bhh[gc];
            }
        }
    }
}

// ---------- k_rec2: one LSTM step. 64 WGs x 512 thr; wave=(gate v, K-half); cell fused ----------
__global__ __launch_bounds__(512) void k_rec2(
    const float* __restrict__ gx,
    const ushort* __restrict__ Whi, const ushort* __restrict__ Wlo,
    ushort* __restrict__ hxA_hi, ushort* __restrict__ hxA_lo,
    float* __restrict__ hxh, float* __restrict__ cx, int t) {
    __shared__ float sg[2][4][32][16];
    int w = blockIdx.x, tid = threadIdx.x;
    int wave = tid >> 6, lane = tid & 63;
    int v = wave & 3, kh = wave >> 2;
    int r16 = lane & 15, kg = lane >> 4;
    int p = t & 1, q = p ^ 1;
    const ushort* Ah = hxA_hi + p * 32768;
    const ushort* Al = hxA_lo + p * 32768;
    int j = v * 1024 + w * 16 + r16;
    const ushort* bhp = Whi + (long)j * 1024;
    const ushort* blp = Wlo + (long)j * 1024;
    f32x4 acc0 = {0.f, 0.f, 0.f, 0.f}, acc1 = {0.f, 0.f, 0.f, 0.f};
    int kbase = kh * 512 + kg * 8;
#pragma unroll 4
    for (int it = 0; it < 16; ++it) {
        int k0 = kbase + it * 32;
        bf16x8 a_h0 = *(const bf16x8*)(Ah + r16 * 1024 + k0);
        bf16x8 a_l0 = *(const bf16x8*)(Al + r16 * 1024 + k0);
        bf16x8 a_h1 = *(const bf16x8*)(Ah + (16 + r16) * 1024 + k0);
        bf16x8 a_l1 = *(const bf16x8*)(Al + (16 + r16) * 1024 + k0);
        bf16x8 b_h = *(const bf16x8*)(bhp + k0);
        bf16x8 b_l = *(const bf16x8*)(blp + k0);
        acc0 = __builtin_amdgcn_mfma_f32_16x16x32_bf16(a_h0, b_h, acc0, 0, 0, 0);
        acc0 = __builtin_amdgcn_mfma_f32_16x16x32_bf16(a_l0, b_h, acc0, 0, 0, 0);
        acc0 = __builtin_amdgcn_mfma_f32_16x16x32_bf16(a_h0, b_l, acc0, 0, 0, 0);
        acc1 = __builtin_amdgcn_mfma_f32_16x16x32_bf16(a_h1, b_h, acc1, 0, 0, 0);
        acc1 = __builtin_amdgcn_mfma_f32_16x16x32_bf16(a_l1, b_h, acc1, 0, 0, 0);
        acc1 = __builtin_amdgcn_mfma_f32_16x16x32_bf16(a_h1, b_l, acc1, 0, 0, 0);
    }
#pragma unroll
    for (int reg = 0; reg < 4; ++reg) {
        sg[kh][v][kg * 4 + reg][r16]      = acc0[reg];
        sg[kh][v][16 + kg * 4 + reg][r16] = acc1[reg];
    }
    __syncthreads();
    // cell: one (b, h16) per thread
    int b = tid >> 4, h16 = tid & 15;
    int hg = w * 16 + h16;
    const float* gxr = gx + ((long)b * Tz + t) * 4096 + hg;
    float gi = sg[0][0][b][h16] + sg[1][0][b][h16] + gxr[0];
    float gf = sg[0][1][b][h16] + sg[1][1][b][h16] + gxr[1024];
    float gg = sg[0][2][b][h16] + sg[1][2][b][h16] + gxr[2048];
    float go = sg[0][3][b][h16] + sg[1][3][b][h16] + gxr[3072];
    long ci = (long)b * Hz + hg;
    float c = sigf(gf) * cx[ci] + sigf(gi) * tanhf(gg);
    float hv = sigf(go) * tanhf(c);
    cx[ci] = c;
    hxh[((long)t * Bz + b) * Hz + hg] = hv;
    ushort hi, lo;
    splitf(hv, hi, lo);
    hxA_hi[q * 32768 + ci] = hi;
    hxA_lo[q * 32768 + ci] = lo;
}

// ---------- k_attn: batched attention for all (b,t); writes AH = [ctx | hx] hi/lo ----------
__global__ __launch_bounds__(256) void k_attn(const float* __restrict__ hxh,
                                              const float* __restrict__ enc,
                                              ushort* __restrict__ AH_hi,
                                              ushort* __restrict__ AH_lo) {
    __shared__ float hxs[Hz];
    __shared__ float sc[64];
    __shared__ float aw[Sz];
    int wid = blockIdx.x, tid = threadIdx.x;
    int b = wid / Tz, t = wid - b * Tz;       // AH row = b*Tz + t = wid
    const float* hsrc = hxh + ((long)t * Bz + b) * Hz;
    *(float4*)&hxs[tid * 4] = *(const float4*)(hsrc + tid * 4);
    __syncthreads();
    int wv = tid >> 6, lane = tid & 63;
    float hreg[16];
#pragma unroll
    for (int u = 0; u < 16; ++u) hreg[u] = hxs[lane * 16 + u];
    const float* eb = enc + (long)b * Sz * Hz;
    for (int s = wv; s < Sz; s += 4) {
        const float* er = eb + (long)s * Hz + lane * 16;
        float sum = 0.f;
#pragma unroll
        for (int qq = 0; qq < 4; ++qq) {
            float4 e4 = *(const float4*)(er + qq * 4);
            sum += e4.x * hreg[qq*4] + e4.y * hreg[qq*4+1] + e4.z * hreg[qq*4+2] + e4.w * hreg[qq*4+3];
        }
#pragma unroll
        for (int off = 32; off >= 1; off >>= 1) sum += __shfl_xor(sum, off);
        if (lane == 0) sc[s] = sum;
    }
    __syncthreads();
    if (tid < 64) {
        float vv = (tid < Sz) ? sc[tid] : -3.402823e38f;
        float mx = vv;
#pragma unroll
        for (int off = 32; off >= 1; off >>= 1) mx = fmaxf(mx, __shfl_xor(mx, off));
        float e = (tid < Sz) ? expf(vv - mx) : 0.f;
        float ssum = e;
#pragma unroll
        for (int off = 32; off >= 1; off >>= 1) ssum += __shfl_xor(ssum, off);
        if (tid < Sz) aw[tid] = e / ssum;
    }
    __syncthreads();
    float c4[4] = {0.f, 0.f, 0.f, 0.f};
#pragma unroll 4
    for (int s = 0; s < Sz; ++s) {
        float4 e4 = *(const float4*)(eb + (long)s * Hz + tid * 4);
        float a = aw[s];
        c4[0] += a * e4.x; c4[1] += a * e4.y; c4[2] += a * e4.z; c4[3] += a * e4.w;
    }
    ushort* dh = AH_hi + (long)wid * 2048;
    ushort* dl = AH_lo + (long)wid * 2048;
#pragma unroll
    for (int u = 0; u < 4; ++u) {
        ushort hi, lo;
        splitf(c4[u], hi, lo);
        dh[tid * 4 + u] = hi;
        dl[tid * 4 + u] = lo;
        splitf(hxs[tid * 4 + u], hi, lo);
        dh[1024 + tid * 4 + u] = hi;
        dl[1024 + tid * 4 + u] = lo;
    }
}

// ---------- k_ht: HXA = tanh(AH @ Wht^T + bht) -> bf16 hi/lo (pre-split B) ----------
__global__ __launch_bounds__(256, 1) void k_ht(const ushort* __restrict__ Ah,
                                               const ushort* __restrict__ Al,
                                               const ushort* __restrict__ Bh,
                                               const ushort* __restrict__ Bl,
                                               const float* __restrict__ bht,
                                               ushort* __restrict__ Hh, ushort* __restrict__ Hl) {
    __shared__ ushort sAh[128][40];
    __shared__ ushort sAl[128][40];
    __shared__ ushort sBh[128][40];
    __shared__ ushort sBl[128][40];
    int bid = blockIdx.x;
    int mt = bid >> 3, nt = bid & 7;
    int tid = threadIdx.x;
    int row = tid >> 1, half = tid & 1;
    int wv = tid >> 6, lane = tid & 63;
    int wr = wv >> 1, wc = wv & 1;
    int m0 = wr * 64, n0 = wc * 64;
    int r16 = lane & 15, kg = lane >> 4, k0 = kg * 8;

    f32x4 acc[4][4];
#pragma unroll
    for (int i = 0; i < 4; i++)
#pragma unroll
        for (int j = 0; j < 4; j++) acc[i][j] = (f32x4){0.f, 0.f, 0.f, 0.f};

    long arow = (long)(mt * 128 + row) * 2048;
    long brow = (long)(nt * 128 + row) * 2048;

    for (int kb = 0; kb < 2048; kb += 32) {
        const ushort* pa = Ah + arow + kb + half * 16;
        *(uint4*)&sAh[row][half * 16]     = *(const uint4*)pa;
        *(uint4*)&sAh[row][half * 16 + 8] = *(const uint4*)(pa + 8);
        const ushort* pl = Al + arow + kb + half * 16;
        *(uint4*)&sAl[row][half * 16]     = *(const uint4*)pl;
        *(uint4*)&sAl[row][half * 16 + 8] = *(const uint4*)(pl + 8);
        const ushort* pb = Bh + brow + kb + half * 16;
        *(uint4*)&sBh[row][half * 16]     = *(const uint4*)pb;
        *(uint4*)&sBh[row][half * 16 + 8] = *(const uint4*)(pb + 8);
        const ushort* pc = Bl + brow + kb + half * 16;
        *(uint4*)&sBl[row][half * 16]     = *(const uint4*)pc;
        *(uint4*)&sBl[row][half * 16 + 8] = *(const uint4*)(pc + 8);
        __syncthreads();
        bf16x8 af[4], alf[4], bhf[4], blf[4];
#pragma unroll
        for (int i = 0; i < 4; ++i) {
            af[i]  = *(const bf16x8*)&sAh[m0 + i * 16 + r16][k0];
            alf[i] = *(const bf16x8*)&sAl[m0 + i * 16 + r16][k0];
            bhf[i] = *(const bf16x8*)&sBh[n0 + i * 16 + r16][k0];
            blf[i] = *(const bf16x8*)&sBl[n0 + i * 16 + r16][k0];
        }
#pragma unroll
        for (int i = 0; i < 4; ++i)
#pragma unroll
            for (int jn = 0; jn < 4; ++jn) {
                acc[i][jn] = __builtin_amdgcn_mfma_f32_16x16x32_bf16(af[i],  bhf[jn], acc[i][jn], 0, 0, 0);
                acc[i][jn] = __builtin_amdgcn_mfma_f32_16x16x32_bf16(af[i],  blf[jn], acc[i][jn], 0, 0, 0);
                acc[i][jn] = __builtin_amdgcn_mfma_f32_16x16x32_bf16(alf[i], bhf[jn], acc[i][jn], 0, 0, 0);
            }
        __syncthreads();
    }
#pragma unroll
    for (int i = 0; i < 4; ++i) {
        int gr0 = mt * 128 + m0 + i * 16 + kg * 4;
#pragma unroll
        for (int reg = 0; reg < 4; ++reg) {
            int gr = gr0 + reg;
            bool valid = gr < Mz;
#pragma unroll
            for (int jn = 0; jn < 4; ++jn) {
                int gc = nt * 128 + n0 + jn * 16 + r16;
                float vv = tanhf(acc[i][jn][reg] + bht[gc]);
                ushort hi = 0, lo = 0;
                if (valid) splitf(vv, hi, lo);
                Hh[(long)gr * Hz + gc] = hi;
                Hl[(long)gr * Hz + gc] = lo;
            }
        }
    }
}

// ---------- k_voc2: logits GEMM (cheap-split bf16 MFMA) + nt stores + fused argmax keys ----------
__global__ __launch_bounds__(256, 1) void k_voc2(
    const ushort* __restrict__ Ah, const ushort* __restrict__ Al,
    const float* __restrict__ W, const float* __restrict__ bvoc,
    float* __restrict__ out, ull* __restrict__ keys) {
    __shared__ ushort sAh[128][40];
    __shared__ ushort sAl[128][40];
    __shared__ ushort sBh[128][40];
    __shared__ ushort sBl[128][40];
    int bid = blockIdx.x;
    int mt = bid / 250, nt = bid % 250;
    int tid = threadIdx.x;
    int row = tid >> 1, half = tid & 1;
    int wv = tid >> 6, lane = tid & 63;
    int wr = wv >> 1, wc = wv & 1;
    int m0 = wr * 64, n0 = wc * 64;
    int r16 = lane & 15, kg = lane >> 4, k0 = kg * 8;

    f32x4 acc[4][4];
#pragma unroll
    for (int i = 0; i < 4; i++)
#pragma unroll
        for (int j = 0; j < 4; j++) acc[i][j] = (f32x4){0.f, 0.f, 0.f, 0.f};

    long arow = (long)(mt * 128 + row) * Hz;
    long wrow = (long)(nt * 128 + row) * Hz;

    for (int kb = 0; kb < Hz; kb += 32) {
        const ushort* pa = Ah + arow + kb + half * 16;
        *(uint4*)&sAh[row][half * 16]     = *(const uint4*)pa;
        *(uint4*)&sAh[row][half * 16 + 8] = *(const uint4*)(pa + 8);
        const ushort* pl = Al + arow + kb + half * 16;
        *(uint4*)&sAl[row][half * 16]     = *(const uint4*)pl;
        *(uint4*)&sAl[row][half * 16 + 8] = *(const uint4*)(pl + 8);
        {
            const float* pw = W + wrow + kb + half * 16;
            ushort hh[16], ll[16];
#pragma unroll
            for (int qq = 0; qq < 16; qq += 4) {
                float4 w4 = *(const float4*)(pw + qq);
                float vv[4] = {w4.x, w4.y, w4.z, w4.w};
#pragma unroll
                for (int e = 0; e < 4; ++e) splitf(vv[e], hh[qq + e], ll[qq + e]);
            }
            *(uint4*)&sBh[row][half * 16]     = *(uint4*)&hh[0];
            *(uint4*)&sBh[row][half * 16 + 8] = *(uint4*)&hh[8];
            *(uint4*)&sBl[row][half * 16]     = *(uint4*)&ll[0];
            *(uint4*)&sBl[row][half * 16 + 8] = *(uint4*)&ll[8];
        }
        __syncthreads();
        bf16x8 af[4], alf[4], bhf[4], blf[4];
#pragma unroll
        for (int i = 0; i < 4; ++i) {
            af[i]  = *(const bf16x8*)&sAh[m0 + i * 16 + r16][k0];
            alf[i] = *(const bf16x8*)&sAl[m0 + i * 16 + r16][k0];
            bhf[i] = *(const bf16x8*)&sBh[n0 + i * 16 + r16][k0];
            blf[i] = *(const bf16x8*)&sBl[n0 + i * 16 + r16][k0];
        }
#pragma unroll
        for (int i = 0; i < 4; ++i)
#pragma unroll
            for (int jn = 0; jn < 4; ++jn) {
                acc[i][jn] = __builtin_amdgcn_mfma_f32_16x16x32_bf16(af[i],  bhf[jn], acc[i][jn], 0, 0, 0);
                acc[i][jn] = __builtin_amdgcn_mfma_f32_16x16x32_bf16(af[i],  blf[jn], acc[i][jn], 0, 0, 0);
                acc[i][jn] = __builtin_amdgcn_mfma_f32_16x16x32_bf16(alf[i], bhf[jn], acc[i][jn], 0, 0, 0);
            }
        __syncthreads();
    }
#pragma unroll
    for (int i = 0; i < 4; ++i) {
        int gr0 = mt * 128 + m0 + i * 16 + kg * 4;
#pragma unroll
        for (int reg = 0; reg < 4; ++reg) {
            int gr = gr0 + reg;
            bool valid = gr < Mz;
            float bestv = -3.402823e38f;
            int bestc = 0;
#pragma unroll
            for (int jn = 0; jn < 4; ++jn) {
                int gc = nt * 128 + n0 + jn * 16 + r16;
                float v = acc[i][jn][reg] + bvoc[gc];
                if (valid) __builtin_nontemporal_store(v, &out[(long)gr * Vz + gc]);
                if (v > bestv) { bestv = v; bestc = gc; }
            }
#pragma unroll
            for (int off = 1; off < 16; off <<= 1) {
                float ov = __shfl_xor(bestv, off);
                int oc = __shfl_xor(bestc, off);
                if (ov > bestv || (ov == bestv && oc < bestc)) { bestv = ov; bestc = oc; }
            }
            if (valid && r16 == 0) {
                uint u = __builtin_bit_cast(uint, bestv);
                u = (u & 0x80000000u) ? ~u : (u | 0x80000000u);
                keys[(long)gr * 512 + nt * 2 + wc] = (((ull)u) << 32) | (ull)(65535 - bestc);
            }
        }
    }
}

__global__ __launch_bounds__(256) void k_argmax2(const ull* __restrict__ keys, float* __restrict__ pred) {
    int r = blockIdx.x, tid = threadIdx.x;
    ull best = 0;
    for (int j = tid; j < 500; j += 256) {
        ull k = keys[(long)r * 512 + j];
        if (k > best) best = k;
    }
    __shared__ ull sk[256];
    sk[tid] = best;
    __syncthreads();
    for (int s = 128; s > 0; s >>= 1) {
        if (tid < s) { if (sk[tid + s] > sk[tid]) sk[tid] = sk[tid + s]; }
        __syncthreads();
    }
    if (tid == 0) pred[r] = (float)(65535 - (int)(sk[0] & 0xFFFFull));
}

// ---------------- host ----------------
extern "C" void kernel_launch(void* const* d_in, const int* in_sizes, int n_in,
                              void* d_out, int out_size, void* d_ws, size_t ws_size,
                              hipStream_t stream) {
    const int*   tok  = (const int*)d_in[0];
    const float* enc  = (const float*)d_in[1];
    const float* h0   = (const float*)d_in[2];
    const float* c0   = (const float*)d_in[3];
    const float* emb  = (const float*)d_in[6];
    const float* Wih  = (const float*)d_in[7];
    const float* Whh  = (const float*)d_in[8];
    const float* bih  = (const float*)d_in[9];
    const float* bhh  = (const float*)d_in[10];
    const float* Wht  = (const float*)d_in[11];
    const float* bht  = (const float*)d_in[12];
    const float* Wvoc = (const float*)d_in[13];
    const float* bvoc = (const float*)d_in[14];
    float* out = (float*)d_out;

    char* base = (char*)d_ws;
    size_t off = 0;
    float*  gx      = (float*)(base + off);  off += (size_t)Mz * 4096 * 4;      // 26,214,400
    ushort* hxA_hi  = (ushort*)(base + off); off += 2 * 32768 * 2;              // [2][32][1024]
    ushort* hxA_lo  = (ushort*)(base + off); off += 2 * 32768 * 2;
    float*  cx      = (float*)(base + off);  off += 32768 * 4;
    float*  hxh     = (float*)(base + off);  off += (size_t)Tz * Bz * Hz * 4;   // [50][32][1024]
    ushort* AH_hi   = (ushort*)(base + off); off += (size_t)Mp * 2048 * 2;
    ushort* AH_lo   = (ushort*)(base + off); off += (size_t)Mp * 2048 * 2;
    ushort* HXA_hi  = (ushort*)(base + off); off += (size_t)Mp * 1024 * 2;
    ushort* HXA_lo  = (ushort*)(base + off); off += (size_t)Mp * 1024 * 2;
    ull*    keys    = (ull*)(base + off);    off += (size_t)Mz * 512 * 8;
    ushort* Whh_hi  = (ushort*)(base + off); off += (size_t)4096 * 1024 * 2;
    ushort* Whh_lo  = (ushort*)(base + off); off += (size_t)4096 * 1024 * 2;
    ushort* Wht_hi  = (ushort*)(base + off); off += (size_t)1024 * 2048 * 2;
    ushort* Wht_lo  = (ushort*)(base + off); off += (size_t)1024 * 2048 * 2;

    k_pre<<<768, 256, 0, stream>>>(hxA_hi, hxA_lo, cx, AH_hi, AH_lo, h0, c0);
    k_wsplit<<<1024, 256, 0, stream>>>(Whh, Whh_hi, Whh_lo, 4096 * 1024 / 4);
    k_wsplit<<<512, 256, 0, stream>>>(Wht, Wht_hi, Wht_lo, 1024 * 2048 / 4);
    k_xgemm<<<13 * 32, 256, 0, stream>>>(emb, tok, Wih, bih, bhh, gx);
    for (int t = 0; t < Tz; ++t) {
        k_rec2<<<64, 512, 0, stream>>>(gx, Whh_hi, Whh_lo, hxA_hi, hxA_lo, hxh, cx, t);
    }
    k_attn<<<Mz, 256, 0, stream>>>(hxh, enc, AH_hi, AH_lo);
    k_ht<<<13 * 8, 256, 0, stream>>>(AH_hi, AH_lo, Wht_hi, Wht_lo, bht, HXA_hi, HXA_lo);
    k_voc2<<<13 * 250, 256, 0, stream>>>(HXA_hi, HXA_lo, Wvoc, bvoc, out, keys);
    k_argmax2<<<Mz, 256, 0, stream>>>(keys, out + (long)Mz * Vz);
}